// Round 13
// baseline (1561.413 us; speedup 1.0000x reference)
//
#include <hip/hip_runtime.h>
#include <math.h>

namespace {

constexpr int nB = 16, nR = 400, nT = 400, nH = 8, nQ = 64;
constexpr int BH = nB * nH;   // 128
constexpr int HQ = nH * nQ;   // 512
constexpr int KP = 416;       // padded K for bf16 GCN GEMM (13 x 32)
constexpr int NK = KP / 32;   // 13 K-chunks

typedef __attribute__((ext_vector_type(8))) short short8;
typedef __attribute__((ext_vector_type(8))) float float8;
typedef __attribute__((ext_vector_type(4))) float floatx4;

__device__ __forceinline__ unsigned short f2bf(float f) {
  unsigned int u = __float_as_uint(f);
  unsigned int r = (u + 0x7fffu + ((u >> 16) & 1u)) >> 16;
  return (unsigned short)r;
}
__device__ __forceinline__ float bf2f(unsigned short u) {
  return __uint_as_float(((unsigned int)u) << 16);
}

// ---------------- generic fp32 GEMM: C = act(A@W + bias) ----------------
template<int BM, int BN, int BK, int TM, int TN, bool RELU>
__global__ __launch_bounds__(256) void gemm_k(
    const float* __restrict__ A, const float* __restrict__ W,
    const float* __restrict__ bias,
    float* C, int M, int N, int K)
{
  constexpr int NT = (BM / TM) * (BN / TN);
  static_assert(NT == 256, "block must be 256 threads");
  __shared__ float As[BK][BM + 4];
  __shared__ float Bs[BK][BN + 4];
  const int tid = threadIdx.x;
  const int bm = blockIdx.y * BM;
  const int bn = blockIdx.x * BN;
  const int tx = tid % (BN / TN);
  const int ty = tid / (BN / TN);
  const bool n4ok = ((N & 3) == 0);

  float acc[TM][TN];
#pragma unroll
  for (int i = 0; i < TM; ++i)
#pragma unroll
    for (int j = 0; j < TN; ++j) acc[i][j] = 0.f;

  for (int kt = 0; kt < K; kt += BK) {
#pragma unroll
    for (int i = 0; i < (BM * BK) / (NT * 4); ++i) {
      int flat = (tid + i * NT) * 4;
      int m = flat / BK;
      int k = flat % BK;
      float4 v = *(const float4*)(A + (size_t)(bm + m) * K + kt + k);
      As[k + 0][m] = v.x; As[k + 1][m] = v.y;
      As[k + 2][m] = v.z; As[k + 3][m] = v.w;
    }
#pragma unroll
    for (int i = 0; i < (BK * BN) / (NT * 4); ++i) {
      int flat = (tid + i * NT) * 4;
      int k = flat / BN;
      int n = flat % BN;
      int gn = bn + n;
      float4 v;
      if (n4ok && gn + 3 < N) {
        v = *(const float4*)(W + (size_t)(kt + k) * N + gn);
      } else {
        v.x = (gn + 0 < N) ? W[(size_t)(kt + k) * N + gn + 0] : 0.f;
        v.y = (gn + 1 < N) ? W[(size_t)(kt + k) * N + gn + 1] : 0.f;
        v.z = (gn + 2 < N) ? W[(size_t)(kt + k) * N + gn + 2] : 0.f;
        v.w = (gn + 3 < N) ? W[(size_t)(kt + k) * N + gn + 3] : 0.f;
      }
      *(float4*)&Bs[k][n] = v;
    }
    __syncthreads();
#pragma unroll
    for (int k = 0; k < BK; ++k) {
      float a[TM], b[TN];
#pragma unroll
      for (int i = 0; i < TM; i += 4)
        *(float4*)&a[i] = *(const float4*)&As[k][ty * TM + i];
#pragma unroll
      for (int j = 0; j < TN; j += 4)
        *(float4*)&b[j] = *(const float4*)&Bs[k][tx * TN + j];
#pragma unroll
      for (int i = 0; i < TM; ++i)
#pragma unroll
        for (int j = 0; j < TN; ++j) acc[i][j] += a[i] * b[j];
    }
    __syncthreads();
  }

#pragma unroll
  for (int i = 0; i < TM; ++i) {
    const int gm = bm + ty * TM + i;
    float* crow = C + (size_t)gm * N;
#pragma unroll
    for (int j = 0; j < TN; j += 4) {
      const int gn = bn + tx * TN + j;
      if (n4ok && gn + 3 < N) {
        float4 bv = *(const float4*)(bias + gn);
        float4 v;
        v.x = acc[i][j + 0] + bv.x; v.y = acc[i][j + 1] + bv.y;
        v.z = acc[i][j + 2] + bv.z; v.w = acc[i][j + 3] + bv.w;
        if (RELU) {
          v.x = fmaxf(v.x, 0.f); v.y = fmaxf(v.y, 0.f);
          v.z = fmaxf(v.z, 0.f); v.w = fmaxf(v.w, 0.f);
        }
        *(float4*)(crow + gn) = v;
      } else {
#pragma unroll
        for (int jj = 0; jj < 4; ++jj) {
          int gnn = gn + jj;
          if (gnn < N) {
            float v = acc[i][j + jj] + bias[gnn];
            if (RELU) v = fmaxf(v, 0.f);
            crow[gnn] = v;
          }
        }
      }
    }
  }
}

// ---------------- GCN step 1: G = feats @ W (bf16 out, no epilogue math) ------
// Associativity restructure: (A_sp@feats)@W == A_sp@(feats@W). This GEMM has no
// residual chain; A (feats fp32) is cvt'd to bf16 fragments on the fly (RNE).
// K-cols 400..415 read past-row garbage (finite) x Wt zero rows -> exact 0.
// Barrier-free K-loop, depth-1 register pipeline, XCD-local grid (m on x).
__global__ __launch_bounds__(256, 3) void gemmG_k(
    const float* __restrict__ A,            // [M][400] fp32
    const unsigned short* __restrict__ Bt,  // [416][416] bf16 n-major
    unsigned short* __restrict__ G)         // [M][416] bf16
{
  __shared__ unsigned short Os[64 * 72];    // 9.2 KB bounce

  const int tid = threadIdx.x;
  const int lane = tid & 63;
  const int wave = tid >> 6;
  const int bm = blockIdx.x * 128;
  const int bn = blockIdx.y * 64;           // 7 tiles cover 448; store guard <416
  const int wm = (wave & 1) * 64;
  const int wn = (wave >> 1) * 32;

  const int fr = lane & 15;
  const int fk = (lane >> 4) * 8;

  const float* Ap[4];
#pragma unroll
  for (int mi = 0; mi < 4; ++mi)
    Ap[mi] = A + (size_t)(bm + wm + mi * 16 + fr) * 400 + fk;
  const unsigned short* Bp[2];
#pragma unroll
  for (int ni = 0; ni < 2; ++ni) {
    int row = bn + wn + ni * 16 + fr;
    if (row > 415) row = 415;               // zero-pad row of Wt
    Bp[ni] = Bt + (size_t)row * KP + fk;
  }

  floatx4 acc[4][2] = {};
  float8 af[2][4];
  short8 bb[2][2];

#pragma unroll
  for (int mi = 0; mi < 4; ++mi) af[0][mi] = *(const float8*)(Ap[mi]);
#pragma unroll
  for (int ni = 0; ni < 2; ++ni) bb[0][ni] = *(const short8*)(Bp[ni]);

#pragma unroll
  for (int k = 0; k < NK; ++k) {
    const int cur = k & 1, nxt = (k + 1) & 1;
    if (k + 1 < NK) {
#pragma unroll
      for (int mi = 0; mi < 4; ++mi)
        af[nxt][mi] = *(const float8*)(Ap[mi] + (k + 1) * 32);
#pragma unroll
      for (int ni = 0; ni < 2; ++ni)
        bb[nxt][ni] = *(const short8*)(Bp[ni] + (k + 1) * 32);
    }
    short8 a[4];
#pragma unroll
    for (int mi = 0; mi < 4; ++mi)
#pragma unroll
      for (int e = 0; e < 8; ++e)
        a[mi][e] = (short)f2bf(af[cur][mi][e]);
#pragma unroll
    for (int mi = 0; mi < 4; ++mi)
#pragma unroll
      for (int ni = 0; ni < 2; ++ni)
        acc[mi][ni] = __builtin_amdgcn_mfma_f32_16x16x32_bf16(
            a[mi], bb[cur][ni], acc[mi][ni], 0, 0, 0);
  }

  // 2 row-half passes: owning waves write bf16(acc) -> Os; cooperative store.
  for (int rh = 0; rh < 2; ++rh) {
    __syncthreads();
    if (wm == rh * 64) {
#pragma unroll
      for (int mi = 0; mi < 4; ++mi)
#pragma unroll
        for (int ni = 0; ni < 2; ++ni)
#pragma unroll
          for (int r = 0; r < 4; ++r) {
            const int lrow = mi * 16 + (lane >> 4) * 4 + r;
            const int cl = wn + ni * 16 + (lane & 15);
            Os[lrow * 72 + cl] = f2bf(acc[mi][ni][r]);
          }
    }
    __syncthreads();

#pragma unroll
    for (int ii = 0; ii < 4; ++ii) {
      const int f = tid + ii * 256;   // 0..1023
      const int row = f >> 4;         // 0..63
      const int c4 = (f & 15) * 4;    // 0..60
      const int col = bn + c4;
      if (col < KP) {
        const int gr = bm + rh * 64 + row;
        ushort4 v = *(const ushort4*)&Os[row * 72 + c4];
        *(ushort4*)(G + (size_t)gr * KP + col) = v;
      }
    }
  }
}

// ---------------- GCN step 2: feats = relu(A_sp @ G + bias) + residual --------
// LDS-staged 32-col chunk of G[bh] (bf16); 7-sparse gather in fp32 (bf16->fp32
// expansion is exact); fuses bias + relu + residual (x for layer 0).
__global__ __launch_bounds__(256) void gatherG_k(
    const int* __restrict__ adjcol, const float* __restrict__ adjval,
    const unsigned short* __restrict__ G, const float* __restrict__ bias,
    const float* __restrict__ x, float* __restrict__ feats, int first)
{
  __shared__ unsigned short gs[400 * 36];   // 28.8 KB, row stride 36 shorts

  const int tid = threadIdx.x;
  const int bh = blockIdx.y;
  const int c0 = blockIdx.x * 32;
  const unsigned short* gsl = G + (size_t)(first ? (bh >> 3) * nR : bh * nR) * KP;

  // stage: 400 rows x 32 cols bf16 (8B units)
  for (int f = tid; f < 3200; f += 256) {
    const int r = f >> 3, cg8 = f & 7;             // 4-col groups
    const int c = c0 + cg8 * 4;
    *(ushort4*)&gs[r * 36 + cg8 * 4] = *(const ushort4*)(gsl + (size_t)r * KP + c);
  }
  __syncthreads();

  const int* ac = adjcol + (size_t)bh * nR * 8;
  const float* av = adjval + (size_t)bh * nR * 8;
  const float* res = first ? (x + (size_t)(bh >> 3) * (nR * nT))
                           : (feats + (size_t)bh * (size_t)nR * nT);

  for (int f = tid; f < 1600; f += 256) {
    const int r = f >> 2, cg = f & 3;
    const int c = c0 + cg * 8;                      // 8 output cols
    if (c >= nT) continue;                          // chunk 12: cols 400..415 pad
    float a8[8] = {};
#pragma unroll
    for (int j = 0; j < 7; ++j) {
      const int col = ac[r * 8 + j];
      const float val = av[r * 8 + j];
      const unsigned short* gp = &gs[col * 36 + cg * 8];
#pragma unroll
      for (int e = 0; e < 8; ++e) a8[e] += val * bf2f(gp[e]);
    }
    const float* rr = res + (size_t)r * nT + c;
    float* orow = feats + ((size_t)bh * nR + r) * nT + c;
    float4 o0, o1;
    o0.x = fmaxf(a8[0] + bias[c + 0], 0.f) + rr[0];
    o0.y = fmaxf(a8[1] + bias[c + 1], 0.f) + rr[1];
    o0.z = fmaxf(a8[2] + bias[c + 2], 0.f) + rr[2];
    o0.w = fmaxf(a8[3] + bias[c + 3], 0.f) + rr[3];
    o1.x = fmaxf(a8[4] + bias[c + 4], 0.f) + rr[4];
    o1.y = fmaxf(a8[5] + bias[c + 5], 0.f) + rr[5];
    o1.z = fmaxf(a8[6] + bias[c + 6], 0.f) + rr[6];
    o1.w = fmaxf(a8[7] + bias[c + 7], 0.f) + rr[7];
    *(float4*)orow = o0;
    *(float4*)(orow + 4) = o1;
  }
}

// ---------------- W prep: Wt[i][n][k] = bf16(gcn_W[i][k][n]), zero-padded ------
__global__ void wprep_k(const float* __restrict__ W, unsigned short* __restrict__ Wt)
{
  __shared__ float t[32][33];
  const int i = blockIdx.z;
  const int k0 = blockIdx.x * 32;
  const int n0 = blockIdx.y * 32;
  const int tx = threadIdx.x, ty = threadIdx.y;   // 32 x 8
#pragma unroll
  for (int r = 0; r < 32; r += 8) {
    int k = k0 + ty + r, n = n0 + tx;
    t[ty + r][tx] = (k < nT && n < nT) ? W[(size_t)i * nT * nT + (size_t)k * nT + n] : 0.f;
  }
  __syncthreads();
#pragma unroll
  for (int r = 0; r < 32; r += 8) {
    int n = n0 + ty + r, k = k0 + tx;
    Wt[(size_t)i * KP * KP + (size_t)n * KP + k] = f2bf(t[tx][ty + r]);
  }
}

// ---------------- SE gate (gap == 1/R identically) -----------------------------
__global__ void gate_k(const float* __restrict__ w1, const float* __restrict__ b1,
                       const float* __restrict__ w2, const float* __restrict__ b2,
                       float* gate)
{
  if (threadIdx.x == 0 && blockIdx.x == 0) {
    float h1[4];
    const float gap = 1.0f / 400.0f;
#pragma unroll
    for (int i = 0; i < 4; ++i) {
      float s = b1[i];
      for (int h = 0; h < 8; ++h) s += gap * w1[h * 4 + i];
      h1[i] = fmaxf(s, 0.f);
    }
#pragma unroll
    for (int h = 0; h < 8; ++h) {
      float s = b2[h];
      for (int i = 0; i < 4; ++i) s += h1[i] * w2[i * 8 + h];
      gate[h] = 1.f / (1.f + expf(-s));
    }
  }
}

// ---------------- batched QK^T scores: sc = relu((Q@K^T)/8), symmetric ---------
__global__ __launch_bounds__(256) void qkscore_k(
    const float* __restrict__ qk, float* __restrict__ sc)
{
  __shared__ float Qs[64][68];   // Qs[k][m]
  __shared__ float Ks[64][68];   // Ks[k][n]

  const int tm = blockIdx.y;
  const int tn = blockIdx.x;
  if (tm > tn) return;           // symmetry: skip lower triangle

  const int tid = threadIdx.x;
  const int bh = blockIdx.z;
  const int b = bh >> 3, h = bh & 7;
  const int bm = tm * 64;
  const int bn = tn * 64;
  const float* qkb = qk + (size_t)b * nR * HQ + h * nQ;

  {
    const int row = tid & 63;
#pragma unroll
    for (int p = 0; p < 4; ++p) {
      const int kc = (tid >> 6) + p * 4;
      int gr = bm + row; if (gr > 399) gr = 399;
      float4 v = *(const float4*)(qkb + (size_t)gr * HQ + (kc << 2));
      Qs[kc * 4 + 0][row] = v.x; Qs[kc * 4 + 1][row] = v.y;
      Qs[kc * 4 + 2][row] = v.z; Qs[kc * 4 + 3][row] = v.w;
      int gs2 = bn + row; if (gs2 > 399) gs2 = 399;
      float4 w = *(const float4*)(qkb + (size_t)gs2 * HQ + (kc << 2));
      Ks[kc * 4 + 0][row] = w.x; Ks[kc * 4 + 1][row] = w.y;
      Ks[kc * 4 + 2][row] = w.z; Ks[kc * 4 + 3][row] = w.w;
    }
  }
  __syncthreads();

  const int tx = tid & 15;
  const int ty = tid >> 4;
  float acc[4][4] = {};
#pragma unroll 8
  for (int k = 0; k < 64; ++k) {
    float4 a = *(const float4*)&Qs[k][ty * 4];
    float4 bv = *(const float4*)&Ks[k][tx * 4];
    acc[0][0] += a.x * bv.x; acc[0][1] += a.x * bv.y; acc[0][2] += a.x * bv.z; acc[0][3] += a.x * bv.w;
    acc[1][0] += a.y * bv.x; acc[1][1] += a.y * bv.y; acc[1][2] += a.y * bv.z; acc[1][3] += a.y * bv.w;
    acc[2][0] += a.z * bv.x; acc[2][1] += a.z * bv.y; acc[2][2] += a.z * bv.z; acc[2][3] += a.z * bv.w;
    acc[3][0] += a.w * bv.x; acc[3][1] += a.w * bv.y; acc[3][2] += a.w * bv.z; acc[3][3] += a.w * bv.w;
  }

  float* scb = sc + (size_t)bh * nR * 400;

  {
    const int gc = bn + tx * 4;
    if (gc < 400) {
#pragma unroll
      for (int i = 0; i < 4; ++i) {
        const int gr = bm + ty * 4 + i;
        if (gr < 400) {
          float4 o;
          o.x = fmaxf(acc[i][0] * 0.125f, 0.f);
          o.y = fmaxf(acc[i][1] * 0.125f, 0.f);
          o.z = fmaxf(acc[i][2] * 0.125f, 0.f);
          o.w = fmaxf(acc[i][3] * 0.125f, 0.f);
          *(float4*)(scb + (size_t)gr * 400 + gc) = o;
        }
      }
    }
  }

  if (tm != tn) {
    const int gc = bm + ty * 4;
    if (gc < 400) {
#pragma unroll
      for (int j = 0; j < 4; ++j) {
        const int gr = bn + tx * 4 + j;
        if (gr < 400) {
          float4 o;
          o.x = fmaxf(acc[0][j] * 0.125f, 0.f);
          o.y = fmaxf(acc[1][j] * 0.125f, 0.f);
          o.z = fmaxf(acc[2][j] * 0.125f, 0.f);
          o.w = fmaxf(acc[3][j] * 0.125f, 0.f);
          *(float4*)(scb + (size_t)gr * 400 + gc) = o;
        }
      }
    }
  }
}

// ---------------- softmax + gate + stable-rank mask -> sparse adj --------------
__global__ __launch_bounds__(256) void rankadj_k(
    const float* __restrict__ sc, const float* __restrict__ gate,
    float* __restrict__ adjval, int* __restrict__ adjcol)
{
  __shared__ float rowbuf[4][408];

  const int wave = threadIdx.x >> 6;
  const int lane = threadIdx.x & 63;
  const int row = blockIdx.x * 4 + wave;
  const int bh = row / nR;
  const int r = row - bh * nR;
  const float* srow = sc + (size_t)row * 400;

  float v[7];
  bool valid[7];
#pragma unroll
  for (int it = 0; it < 7; ++it) {
    const int j = lane + it * 64;
    valid[it] = (j < 400);
    v[it] = valid[it] ? srow[j] : 0.f;
  }

  float m = 0.f;
#pragma unroll
  for (int it = 0; it < 7; ++it) m = fmaxf(m, v[it]);
#pragma unroll
  for (int o = 32; o > 0; o >>= 1) m = fmaxf(m, __shfl_xor(m, o));

  float e[7];
  float s = 0.f;
#pragma unroll
  for (int it = 0; it < 7; ++it) {
    e[it] = valid[it] ? expf(v[it] - m) : 0.f;
    s += e[it];
  }
#pragma unroll
  for (int o = 32; o > 0; o >>= 1) s += __shfl_xor(s, o);

  const float g = gate[bh & 7];
  float val[7];
#pragma unroll
  for (int it = 0; it < 7; ++it) val[it] = (e[it] / s) * g;

#pragma unroll
  for (int it = 0; it < 7; ++it)
    if (valid[it]) rowbuf[wave][lane + it * 64] = val[it];
  __syncthreads();

  const int csp[6] = {0, 16, 17, 18, 19, 20};
  float vc[6];
#pragma unroll
  for (int i = 0; i < 6; ++i) vc[i] = rowbuf[wave][csp[i]];
  int rk[6] = {0, 0, 0, 0, 0, 0};
#pragma unroll
  for (int it = 0; it < 7; ++it) {
    if (valid[it]) {
      const int j = lane + it * 64;
      const float vj = val[it];
#pragma unroll
      for (int i = 0; i < 6; ++i)
        rk[i] += (vj < vc[i]) ? 1 : ((vj == vc[i] && j < csp[i]) ? 1 : 0);
    }
  }
#pragma unroll
  for (int i = 0; i < 6; ++i)
#pragma unroll
    for (int o = 32; o > 0; o >>= 1) rk[i] += __shfl_xor(rk[i], o);

  if (lane == 0) {
    const size_t base = (size_t)row * 8;
    bool dup = false;
#pragma unroll
    for (int i = 0; i < 6; ++i) {
      const int p = rk[i];
      adjcol[base + i] = p;
      adjval[base + i] = rowbuf[wave][p];
      dup = dup || (p == r);
    }
    adjcol[base + 6] = r;
    adjval[base + 6] = dup ? 0.f : rowbuf[wave][r];
    adjcol[base + 7] = r;
    adjval[base + 7] = 0.f;
  }
}

// ---------------- head fusion ---------------------------------------------------
__global__ void hfuse_k(const float* __restrict__ feats, const float* __restrict__ fw,
                        const float* __restrict__ fb, float* __restrict__ fused)
{
  size_t i = (size_t)blockIdx.x * 256 + threadIdx.x;
  constexpr size_t tot4 = (size_t)nB * nR * nT / 4;
  if (i >= tot4) return;
  size_t b = i / (nR * nT / 4);
  size_t rem = i % (nR * nT / 4);
  float fbv = fb[0];
  float4 acc = {fbv, fbv, fbv, fbv};
#pragma unroll
  for (int h = 0; h < nH; ++h) {
    float w = fw[h];
    float4 v = ((const float4*)feats)[(b * nH + h) * (nR * nT / 4) + rem];
    acc.x += w * v.x; acc.y += w * v.y; acc.z += w * v.z; acc.w += w * v.w;
  }
  ((float4*)fused)[i] = acc;
}

}  // namespace

extern "C" void kernel_launch(void* const* d_in, const int* in_sizes, int n_in,
                              void* d_out, int out_size, void* d_ws, size_t ws_size,
                              hipStream_t stream)
{
  (void)in_sizes; (void)n_in; (void)out_size; (void)ws_size;
  const float* x    = (const float*)d_in[0];
  const float* Wk   = (const float*)d_in[1];
  const float* bk   = (const float*)d_in[2];
  const float* seW1 = (const float*)d_in[3];
  const float* seb1 = (const float*)d_in[4];
  const float* seW2 = (const float*)d_in[5];
  const float* seb2 = (const float*)d_in[6];
  const float* gcnW = (const float*)d_in[7];
  const float* gcnb = (const float*)d_in[8];
  const float* fw   = (const float*)d_in[9];
  const float* fb   = (const float*)d_in[10];
  const float* mW1  = (const float*)d_in[11];
  const float* mb1  = (const float*)d_in[12];
  const float* mW2  = (const float*)d_in[13];
  const float* mb2  = (const float*)d_in[14];
  const float* mW3  = (const float*)d_in[15];
  const float* mb3  = (const float*)d_in[16];
  const float* mW4  = (const float*)d_in[17];
  const float* mb4  = (const float*)d_in[18];
  float* out = (float*)d_out;

  // workspace (float units), total ~130.6 MB (+64B slack after feats)
  float* ws     = (float*)d_ws;
  float* adjval = ws;                                         //   409,600
  int*   adjcol = (int*)(adjval + 409600);                    //   409,600
  float* gate   = (float*)(adjcol + 409600);                  //        64
  unsigned short* Wt = (unsigned short*)(gate + 64);          //   692,224 f
  float* feats  = gate + 64 + 692224;                         // 20,480,000 f
  float* big    = feats + (size_t)20480016;                   // +16 slack (finite poison)
  float* qk     = big;                                        // 3,276,800 f
  unsigned short* G = (unsigned short*)big;                   // 51200*416 sh = 10,649,600 f
  float* scores = feats;                                      // aliases feats (dead until GCN)
  float* fused  = big;                                        // MLP aliases dead G
  float* h1     = fused + (size_t)6400 * 400;
  float* h2     = h1 + (size_t)6400 * 256;
  float* h3     = h2 + (size_t)6400 * 128;

  // 0. gcn_W -> bf16, transposed (n-major), zero-padded to 416x416
  wprep_k<<<dim3(13, 13, 8), dim3(32, 8), 0, stream>>>(gcnW, Wt);

  // 1. qk = x @ Wk + bk
  gemm_k<64, 64, 16, 4, 4, false><<<dim3(8, 100), 256, 0, stream>>>(
      x, Wk, bk, qk, 6400, 512, 400);

  // 2. SE gate
  gate_k<<<1, 64, 0, stream>>>(seW1, seb1, seW2, seb2, gate);

  // 3a. batched symmetric QK^T -> relu -> scores [51200,400] (in feats region)
  qkscore_k<<<dim3(7, 7, 128), 256, 0, stream>>>(qk, scores);

  // 3b. softmax+gate+rank -> 7-sparse adjacency (one wave per row)
  rankadj_k<<<12800, 256, 0, stream>>>(scores, gate, adjval, adjcol);

  // 3c. stage x into the (now dead) feats region: layer-0 GEMM A-source.
  hipMemcpyAsync(feats, x, (size_t)6400 * 400 * sizeof(float),
                 hipMemcpyDeviceToDevice, stream);

  // 4. 8x GCN via associativity: G = feats@W (layer0: 6400 rows, x shared
  //    across heads) then feats = relu(A_sp@G + b) + residual.
  for (int i = 0; i < 8; ++i) {
    const int first = (i == 0) ? 1 : 0;
    gemmG_k<<<dim3(first ? 50 : 400, 7), 256, 0, stream>>>(
        feats, Wt + (size_t)i * KP * KP, G);
    gatherG_k<<<dim3(13, BH), 256, 0, stream>>>(
        adjcol, adjval, G, gcnb + (size_t)i * nT, x, feats, first);
  }

  // 5. fuse heads
  hfuse_k<<<2500, 256, 0, stream>>>(feats, fw, fb, fused);

  // 6-9. MLP head (fp32)
  gemm_k<64, 64, 16, 4, 4, true><<<dim3(4, 100), 256, 0, stream>>>(
      fused, mW1, mb1, h1, 6400, 256, 400);
  gemm_k<64, 64, 16, 4, 4, true><<<dim3(2, 100), 256, 0, stream>>>(
      h1, mW2, mb2, h2, 6400, 128, 256);
  gemm_k<64, 64, 16, 4, 4, true><<<dim3(1, 100), 256, 0, stream>>>(
      h2, mW3, mb3, h3, 6400, 64, 128);
  gemm_k<64, 64, 16, 4, 4, true><<<dim3(1, 100), 256, 0, stream>>>(
      h3, mW4, mb4, out, 6400, 5, 64);
}

// Round 14
// 1188.848 us; speedup vs baseline: 1.3134x; 1.3134x over previous
//
#include <hip/hip_runtime.h>
#include <math.h>

namespace {

constexpr int nB = 16, nR = 400, nT = 400, nH = 8, nQ = 64;
constexpr int BH = nB * nH;   // 128
constexpr int HQ = nH * nQ;   // 512
constexpr int KP = 416;       // padded K for bf16 GCN GEMM (13 x 32)
constexpr int NK = KP / 32;   // 13 K-chunks

typedef __attribute__((ext_vector_type(8))) short short8;
typedef __attribute__((ext_vector_type(4))) float floatx4;

__device__ __forceinline__ unsigned short f2bf(float f) {
  unsigned int u = __float_as_uint(f);
  unsigned int r = (u + 0x7fffu + ((u >> 16) & 1u)) >> 16;
  return (unsigned short)r;
}
__device__ __forceinline__ float bf2f(unsigned short u) {
  return __uint_as_float(((unsigned int)u) << 16);
}

// ---------------- generic fp32 GEMM: C = act(A@W + bias) ----------------
template<int BM, int BN, int BK, int TM, int TN, bool RELU>
__global__ __launch_bounds__(256) void gemm_k(
    const float* __restrict__ A, const float* __restrict__ W,
    const float* __restrict__ bias,
    float* C, int M, int N, int K)
{
  constexpr int NT = (BM / TM) * (BN / TN);
  static_assert(NT == 256, "block must be 256 threads");
  __shared__ float As[BK][BM + 4];
  __shared__ float Bs[BK][BN + 4];
  const int tid = threadIdx.x;
  const int bm = blockIdx.y * BM;
  const int bn = blockIdx.x * BN;
  const int tx = tid % (BN / TN);
  const int ty = tid / (BN / TN);
  const bool n4ok = ((N & 3) == 0);

  float acc[TM][TN];
#pragma unroll
  for (int i = 0; i < TM; ++i)
#pragma unroll
    for (int j = 0; j < TN; ++j) acc[i][j] = 0.f;

  for (int kt = 0; kt < K; kt += BK) {
#pragma unroll
    for (int i = 0; i < (BM * BK) / (NT * 4); ++i) {
      int flat = (tid + i * NT) * 4;
      int m = flat / BK;
      int k = flat % BK;
      float4 v = *(const float4*)(A + (size_t)(bm + m) * K + kt + k);
      As[k + 0][m] = v.x; As[k + 1][m] = v.y;
      As[k + 2][m] = v.z; As[k + 3][m] = v.w;
    }
#pragma unroll
    for (int i = 0; i < (BK * BN) / (NT * 4); ++i) {
      int flat = (tid + i * NT) * 4;
      int k = flat / BN;
      int n = flat % BN;
      int gn = bn + n;
      float4 v;
      if (n4ok && gn + 3 < N) {
        v = *(const float4*)(W + (size_t)(kt + k) * N + gn);
      } else {
        v.x = (gn + 0 < N) ? W[(size_t)(kt + k) * N + gn + 0] : 0.f;
        v.y = (gn + 1 < N) ? W[(size_t)(kt + k) * N + gn + 1] : 0.f;
        v.z = (gn + 2 < N) ? W[(size_t)(kt + k) * N + gn + 2] : 0.f;
        v.w = (gn + 3 < N) ? W[(size_t)(kt + k) * N + gn + 3] : 0.f;
      }
      *(float4*)&Bs[k][n] = v;
    }
    __syncthreads();
#pragma unroll
    for (int k = 0; k < BK; ++k) {
      float a[TM], b[TN];
#pragma unroll
      for (int i = 0; i < TM; i += 4)
        *(float4*)&a[i] = *(const float4*)&As[k][ty * TM + i];
#pragma unroll
      for (int j = 0; j < TN; j += 4)
        *(float4*)&b[j] = *(const float4*)&Bs[k][tx * TN + j];
#pragma unroll
      for (int i = 0; i < TM; ++i)
#pragma unroll
        for (int j = 0; j < TN; ++j) acc[i][j] += a[i] * b[j];
    }
    __syncthreads();
  }

#pragma unroll
  for (int i = 0; i < TM; ++i) {
    const int gm = bm + ty * TM + i;
    float* crow = C + (size_t)gm * N;
#pragma unroll
    for (int j = 0; j < TN; j += 4) {
      const int gn = bn + tx * TN + j;
      if (n4ok && gn + 3 < N) {
        float4 bv = *(const float4*)(bias + gn);
        float4 v;
        v.x = acc[i][j + 0] + bv.x; v.y = acc[i][j + 1] + bv.y;
        v.z = acc[i][j + 2] + bv.z; v.w = acc[i][j + 3] + bv.w;
        if (RELU) {
          v.x = fmaxf(v.x, 0.f); v.y = fmaxf(v.y, 0.f);
          v.z = fmaxf(v.z, 0.f); v.w = fmaxf(v.w, 0.f);
        }
        *(float4*)(crow + gn) = v;
      } else {
#pragma unroll
        for (int jj = 0; jj < 4; ++jj) {
          int gnn = gn + jj;
          if (gnn < N) {
            float v = acc[i][j + jj] + bias[gnn];
            if (RELU) v = fmaxf(v, 0.f);
            crow[gnn] = v;
          }
        }
      }
    }
  }
}

// ---------------- bf16 MFMA GEMM for GCN layers — barrier-free K-loop ---------
// R12 structure (direct-global frags, depth-2 register pipeline, XCD-local
// grid m-on-x) with bf16 feats I/O: residual read + feats store are bf16
// (halves epilogue traffic; residual add still fp32, one RNE round per layer).
__global__ __launch_bounds__(256, 4) void gcn_gemm(
    const unsigned short* __restrict__ A,    // msg [51200][416] bf16
    const unsigned short* __restrict__ Bt,   // Wt [416][416] bf16 n-major
    const float* __restrict__ bias,
    unsigned short* __restrict__ Cb,         // feats [51200][400] bf16
    const float* __restrict__ x, int first)
{
  __shared__ float Os[64 * 68];   // 17.4 KB epilogue bounce

  const int tid = threadIdx.x;
  const int lane = tid & 63;
  const int wave = tid >> 6;
  const int bm = blockIdx.x * 128;     // m-tile on x (XCD locality)
  const int bn = blockIdx.y * 64;      // 7 n-tiles cover 448 cols; >=400 pad
  const int wm = (wave & 1) * 64;
  const int wn = (wave >> 1) * 32;

  const int fr = lane & 15;
  const int fk = (lane >> 4) * 8;

  const unsigned short* Ap[4];
  const unsigned short* Bp[2];
#pragma unroll
  for (int mi = 0; mi < 4; ++mi)
    Ap[mi] = A + (size_t)(bm + wm + mi * 16 + fr) * KP + fk;
#pragma unroll
  for (int ni = 0; ni < 2; ++ni) {
    int row = bn + wn + ni * 16 + fr;
    if (row > 415) row = 415;          // zero-pad row of Wt
    Bp[ni] = Bt + (size_t)row * KP + fk;
  }

  floatx4 acc[4][2] = {};
  short8 a[3][4], b[3][2];

#pragma unroll
  for (int mi = 0; mi < 4; ++mi) {
    a[0][mi] = *(const short8*)(Ap[mi]);
    a[1][mi] = *(const short8*)(Ap[mi] + 32);
  }
#pragma unroll
  for (int ni = 0; ni < 2; ++ni) {
    b[0][ni] = *(const short8*)(Bp[ni]);
    b[1][ni] = *(const short8*)(Bp[ni] + 32);
  }

#pragma unroll
  for (int k = 0; k < NK; ++k) {
    const int cur = k % 3;
    const int nxt = (k + 2) % 3;
    if (k + 2 < NK) {
#pragma unroll
      for (int mi = 0; mi < 4; ++mi)
        a[nxt][mi] = *(const short8*)(Ap[mi] + (k + 2) * 32);
#pragma unroll
      for (int ni = 0; ni < 2; ++ni)
        b[nxt][ni] = *(const short8*)(Bp[ni] + (k + 2) * 32);
    }
#pragma unroll
    for (int mi = 0; mi < 4; ++mi)
#pragma unroll
      for (int ni = 0; ni < 2; ++ni)
        acc[mi][ni] = __builtin_amdgcn_mfma_f32_16x16x32_bf16(
            a[cur][mi], b[cur][ni], acc[mi][ni], 0, 0, 0);
  }

  // bias per ni (C/D layout: col = lane&15, row = (lane>>4)*4 + reg)
  float bv[2];
#pragma unroll
  for (int ni = 0; ni < 2; ++ni) {
    const int col = bn + wn + ni * 16 + (lane & 15);
    bv[ni] = (col < nT) ? bias[col] : 0.f;
  }

  // 2 row-half passes: owning waves write relu(acc+bias) fp32 into Os;
  // all 4 waves cooperatively add residual (bf16/x) and store bf16 ushort4.
  for (int rh = 0; rh < 2; ++rh) {
    __syncthreads();
    if (wm == rh * 64) {
#pragma unroll
      for (int mi = 0; mi < 4; ++mi)
#pragma unroll
        for (int ni = 0; ni < 2; ++ni)
#pragma unroll
          for (int r = 0; r < 4; ++r) {
            const int lrow = mi * 16 + (lane >> 4) * 4 + r;
            const int cl = wn + ni * 16 + (lane & 15);
            Os[lrow * 68 + cl] = fmaxf(acc[mi][ni][r] + bv[ni], 0.f);
          }
    }
    __syncthreads();

    const int rbase = bm + rh * 64;
#pragma unroll
    for (int ii = 0; ii < 4; ++ii) {
      const int f = tid + ii * 256;
      const int row = f >> 4;
      const int c4 = (f & 15) << 2;
      const int col = bn + c4;
      if (col < nT) {
        const int gr = rbase + row;
        float4 v = *(const float4*)&Os[row * 68 + c4];
        float r0, r1, r2, r3;
        if (first) {
          const int bh = gr / nR;
          const int rr = gr - bh * nR;
          const float* rrow = x + (size_t)(bh >> 3) * (nR * nT) + (size_t)rr * nT;
          float4 rv = *(const float4*)(rrow + col);
          r0 = rv.x; r1 = rv.y; r2 = rv.z; r3 = rv.w;
        } else {
          ushort4 rv = *(const ushort4*)(Cb + (size_t)gr * nT + col);
          r0 = bf2f(rv.x); r1 = bf2f(rv.y); r2 = bf2f(rv.z); r3 = bf2f(rv.w);
        }
        ushort4 o;
        o.x = f2bf(v.x + r0); o.y = f2bf(v.y + r1);
        o.z = f2bf(v.z + r2); o.w = f2bf(v.w + r3);
        *(ushort4*)(Cb + (size_t)gr * nT + col) = o;
      }
    }
  }
}

// ---------------- W prep: Wt[i][n][k] = bf16(gcn_W[i][k][n]), zero-padded ------
__global__ void wprep_k(const float* __restrict__ W, unsigned short* __restrict__ Wt)
{
  __shared__ float t[32][33];
  const int i = blockIdx.z;
  const int k0 = blockIdx.x * 32;
  const int n0 = blockIdx.y * 32;
  const int tx = threadIdx.x, ty = threadIdx.y;   // 32 x 8
#pragma unroll
  for (int r = 0; r < 32; r += 8) {
    int k = k0 + ty + r, n = n0 + tx;
    t[ty + r][tx] = (k < nT && n < nT) ? W[(size_t)i * nT * nT + (size_t)k * nT + n] : 0.f;
  }
  __syncthreads();
#pragma unroll
  for (int r = 0; r < 32; r += 8) {
    int n = n0 + ty + r, k = k0 + tx;
    Wt[(size_t)i * KP * KP + (size_t)n * KP + k] = f2bf(t[tx][ty + r]);
  }
}

// ---------------- SE gate (gap == 1/R identically) -----------------------------
__global__ void gate_k(const float* __restrict__ w1, const float* __restrict__ b1,
                       const float* __restrict__ w2, const float* __restrict__ b2,
                       float* gate)
{
  if (threadIdx.x == 0 && blockIdx.x == 0) {
    float h1[4];
    const float gap = 1.0f / 400.0f;
#pragma unroll
    for (int i = 0; i < 4; ++i) {
      float s = b1[i];
      for (int h = 0; h < 8; ++h) s += gap * w1[h * 4 + i];
      h1[i] = fmaxf(s, 0.f);
    }
#pragma unroll
    for (int h = 0; h < 8; ++h) {
      float s = b2[h];
      for (int i = 0; i < 4; ++i) s += h1[i] * w2[i * 8 + h];
      gate[h] = 1.f / (1.f + expf(-s));
    }
  }
}

// ---------------- batched QK^T scores: sc = relu((Q@K^T)/8), symmetric ---------
__global__ __launch_bounds__(256) void qkscore_k(
    const float* __restrict__ qk, float* __restrict__ sc)
{
  __shared__ float Qs[64][68];   // Qs[k][m]
  __shared__ float Ks[64][68];   // Ks[k][n]

  const int tm = blockIdx.y;
  const int tn = blockIdx.x;
  if (tm > tn) return;           // symmetry: skip lower triangle

  const int tid = threadIdx.x;
  const int bh = blockIdx.z;
  const int b = bh >> 3, h = bh & 7;
  const int bm = tm * 64;
  const int bn = tn * 64;
  const float* qkb = qk + (size_t)b * nR * HQ + h * nQ;

  {
    const int row = tid & 63;                 // = lane -> conflict-free LDS writes
#pragma unroll
    for (int p = 0; p < 4; ++p) {
      const int kc = (tid >> 6) + p * 4;
      int gr = bm + row; if (gr > 399) gr = 399;
      float4 v = *(const float4*)(qkb + (size_t)gr * HQ + (kc << 2));
      Qs[kc * 4 + 0][row] = v.x; Qs[kc * 4 + 1][row] = v.y;
      Qs[kc * 4 + 2][row] = v.z; Qs[kc * 4 + 3][row] = v.w;
      int gs2 = bn + row; if (gs2 > 399) gs2 = 399;
      float4 w = *(const float4*)(qkb + (size_t)gs2 * HQ + (kc << 2));
      Ks[kc * 4 + 0][row] = w.x; Ks[kc * 4 + 1][row] = w.y;
      Ks[kc * 4 + 2][row] = w.z; Ks[kc * 4 + 3][row] = w.w;
    }
  }
  __syncthreads();

  const int tx = tid & 15;
  const int ty = tid >> 4;
  float acc[4][4] = {};
#pragma unroll 8
  for (int k = 0; k < 64; ++k) {
    float4 a = *(const float4*)&Qs[k][ty * 4];
    float4 bv = *(const float4*)&Ks[k][tx * 4];
    acc[0][0] += a.x * bv.x; acc[0][1] += a.x * bv.y; acc[0][2] += a.x * bv.z; acc[0][3] += a.x * bv.w;
    acc[1][0] += a.y * bv.x; acc[1][1] += a.y * bv.y; acc[1][2] += a.y * bv.z; acc[1][3] += a.y * bv.w;
    acc[2][0] += a.z * bv.x; acc[2][1] += a.z * bv.y; acc[2][2] += a.z * bv.z; acc[2][3] += a.z * bv.w;
    acc[3][0] += a.w * bv.x; acc[3][1] += a.w * bv.y; acc[3][2] += a.w * bv.z; acc[3][3] += a.w * bv.w;
  }

  float* scb = sc + (size_t)bh * nR * 400;

  {
    const int gc = bn + tx * 4;
    if (gc < 400) {
#pragma unroll
      for (int i = 0; i < 4; ++i) {
        const int gr = bm + ty * 4 + i;
        if (gr < 400) {
          float4 o;
          o.x = fmaxf(acc[i][0] * 0.125f, 0.f);
          o.y = fmaxf(acc[i][1] * 0.125f, 0.f);
          o.z = fmaxf(acc[i][2] * 0.125f, 0.f);
          o.w = fmaxf(acc[i][3] * 0.125f, 0.f);
          *(float4*)(scb + (size_t)gr * 400 + gc) = o;
        }
      }
    }
  }

  if (tm != tn) {
    const int gc = bm + ty * 4;
    if (gc < 400) {
#pragma unroll
      for (int j = 0; j < 4; ++j) {
        const int gr = bn + tx * 4 + j;
        if (gr < 400) {
          float4 o;
          o.x = fmaxf(acc[0][j] * 0.125f, 0.f);
          o.y = fmaxf(acc[1][j] * 0.125f, 0.f);
          o.z = fmaxf(acc[2][j] * 0.125f, 0.f);
          o.w = fmaxf(acc[3][j] * 0.125f, 0.f);
          *(float4*)(scb + (size_t)gr * 400 + gc) = o;
        }
      }
    }
  }
}

// ---------------- softmax + gate + stable-rank mask -> sparse adj --------------
__global__ __launch_bounds__(256) void rankadj_k(
    const float* __restrict__ sc, const float* __restrict__ gate,
    float* __restrict__ adjval, int* __restrict__ adjcol)
{
  __shared__ float rowbuf[4][408];

  const int wave = threadIdx.x >> 6;
  const int lane = threadIdx.x & 63;
  const int row = blockIdx.x * 4 + wave;
  const int bh = row / nR;
  const int r = row - bh * nR;
  const float* srow = sc + (size_t)row * 400;

  float v[7];
  bool valid[7];
#pragma unroll
  for (int it = 0; it < 7; ++it) {
    const int j = lane + it * 64;
    valid[it] = (j < 400);
    v[it] = valid[it] ? srow[j] : 0.f;
  }

  float m = 0.f;
#pragma unroll
  for (int it = 0; it < 7; ++it) m = fmaxf(m, v[it]);
#pragma unroll
  for (int o = 32; o > 0; o >>= 1) m = fmaxf(m, __shfl_xor(m, o));

  float e[7];
  float s = 0.f;
#pragma unroll
  for (int it = 0; it < 7; ++it) {
    e[it] = valid[it] ? expf(v[it] - m) : 0.f;
    s += e[it];
  }
#pragma unroll
  for (int o = 32; o > 0; o >>= 1) s += __shfl_xor(s, o);

  const float g = gate[bh & 7];
  float val[7];
#pragma unroll
  for (int it = 0; it < 7; ++it) val[it] = (e[it] / s) * g;

#pragma unroll
  for (int it = 0; it < 7; ++it)
    if (valid[it]) rowbuf[wave][lane + it * 64] = val[it];
  __syncthreads();

  const int csp[6] = {0, 16, 17, 18, 19, 20};
  float vc[6];
#pragma unroll
  for (int i = 0; i < 6; ++i) vc[i] = rowbuf[wave][csp[i]];
  int rk[6] = {0, 0, 0, 0, 0, 0};
#pragma unroll
  for (int it = 0; it < 7; ++it) {
    if (valid[it]) {
      const int j = lane + it * 64;
      const float vj = val[it];
#pragma unroll
      for (int i = 0; i < 6; ++i)
        rk[i] += (vj < vc[i]) ? 1 : ((vj == vc[i] && j < csp[i]) ? 1 : 0);
    }
  }
#pragma unroll
  for (int i = 0; i < 6; ++i)
#pragma unroll
    for (int o = 32; o > 0; o >>= 1) rk[i] += __shfl_xor(rk[i], o);

  if (lane == 0) {
    const size_t base = (size_t)row * 8;
    bool dup = false;
#pragma unroll
    for (int i = 0; i < 6; ++i) {
      const int p = rk[i];
      adjcol[base + i] = p;
      adjval[base + i] = rowbuf[wave][p];
      dup = dup || (p == r);
    }
    adjcol[base + 6] = r;
    adjval[base + 6] = dup ? 0.f : rowbuf[wave][r];
    adjcol[base + 7] = r;
    adjval[base + 7] = 0.f;
  }
}

// ---------------- sparse msg via LDS-staged feats(bf16) column-chunks ----------
// 16-col chunks (grid 26 x 128); fs bf16 stride 20 shorts -> LDS 16 KB.
__global__ __launch_bounds__(256) void spmsg_k(
    const int* __restrict__ adjcol, const float* __restrict__ adjval,
    const unsigned short* __restrict__ feats, const float* __restrict__ x,
    int first, unsigned short* __restrict__ msg)
{
  __shared__ unsigned short fs[400 * 20];   // 16 KB

  const int tid = threadIdx.x;
  const int bh = blockIdx.y;
  const int c0 = blockIdx.x * 16;

  if (first) {
    const float* src = x + (size_t)(bh >> 3) * (nR * nT);
    for (int i = tid; i < 1600; i += 256) {
      const int r = i >> 2, cg = i & 3;
      const int c = c0 + cg * 4;
      ushort4 o = make_ushort4(0, 0, 0, 0);
      if (c < 400) {
        float4 v = *(const float4*)(src + (size_t)r * nT + c);
        o = make_ushort4(f2bf(v.x), f2bf(v.y), f2bf(v.z), f2bf(v.w));
      }
      *(ushort4*)&fs[r * 20 + cg * 4] = o;
    }
  } else {
    const unsigned short* src = feats + (size_t)bh * nR * nT;
    for (int i = tid; i < 1600; i += 256) {
      const int r = i >> 2, cg = i & 3;
      const int c = c0 + cg * 4;
      ushort4 o = make_ushort4(0, 0, 0, 0);
      if (c < 400) o = *(const ushort4*)(src + (size_t)r * nT + c);
      *(ushort4*)&fs[r * 20 + cg * 4] = o;
    }
  }
  __syncthreads();

  const int* ac = adjcol + (size_t)bh * nR * 8;
  const float* av = adjval + (size_t)bh * nR * 8;
  for (int i = tid; i < 1600; i += 256) {
    const int r = i >> 2, cg = i & 3;
    float a0 = 0.f, a1 = 0.f, a2 = 0.f, a3 = 0.f;
#pragma unroll
    for (int j = 0; j < 7; ++j) {
      const int col = ac[r * 8 + j];
      const float val = av[r * 8 + j];
      ushort4 v = *(const ushort4*)&fs[col * 20 + cg * 4];
      a0 += val * bf2f(v.x); a1 += val * bf2f(v.y);
      a2 += val * bf2f(v.z); a3 += val * bf2f(v.w);
    }
    unsigned short* o = msg + ((size_t)bh * nR + r) * KP + c0 + cg * 4;
    *(ushort4*)o = make_ushort4(f2bf(a0), f2bf(a1), f2bf(a2), f2bf(a3));
  }
}

// ---------------- head fusion (bf16 feats -> fp32 fused) ------------------------
__global__ void hfuse_k(const unsigned short* __restrict__ feats,
                        const float* __restrict__ fw,
                        const float* __restrict__ fb, float* __restrict__ fused)
{
  size_t i = (size_t)blockIdx.x * 256 + threadIdx.x;   // 4-col groups
  constexpr size_t tot4 = (size_t)nB * nR * nT / 4;    // 640,000
  if (i >= tot4) return;
  size_t b = i / (nR * nT / 4);
  size_t rem = i % (nR * nT / 4);
  float fbv = fb[0];
  float4 acc = {fbv, fbv, fbv, fbv};
#pragma unroll
  for (int h = 0; h < nH; ++h) {
    float w = fw[h];
    ushort4 v = *(const ushort4*)(feats + ((b * nH + h) * (size_t)(nR * nT / 4) + rem) * 4);
    acc.x += w * bf2f(v.x); acc.y += w * bf2f(v.y);
    acc.z += w * bf2f(v.z); acc.w += w * bf2f(v.w);
  }
  ((float4*)fused)[i] = acc;
}

}  // namespace

extern "C" void kernel_launch(void* const* d_in, const int* in_sizes, int n_in,
                              void* d_out, int out_size, void* d_ws, size_t ws_size,
                              hipStream_t stream)
{
  (void)in_sizes; (void)n_in; (void)out_size; (void)ws_size;
  const float* x    = (const float*)d_in[0];
  const float* Wk   = (const float*)d_in[1];
  const float* bk   = (const float*)d_in[2];
  const float* seW1 = (const float*)d_in[3];
  const float* seb1 = (const float*)d_in[4];
  const float* seW2 = (const float*)d_in[5];
  const float* seb2 = (const float*)d_in[6];
  const float* gcnW = (const float*)d_in[7];
  const float* gcnb = (const float*)d_in[8];
  const float* fw   = (const float*)d_in[9];
  const float* fb   = (const float*)d_in[10];
  const float* mW1  = (const float*)d_in[11];
  const float* mb1  = (const float*)d_in[12];
  const float* mW2  = (const float*)d_in[13];
  const float* mb2  = (const float*)d_in[14];
  const float* mW3  = (const float*)d_in[15];
  const float* mb3  = (const float*)d_in[16];
  const float* mW4  = (const float*)d_in[17];
  const float* mb4  = (const float*)d_in[18];
  float* out = (float*)d_out;

  // workspace (float units), total ~103 MB:
  // [adjval][adjcol][gate][Wt][qk][region: scores fp32 (82MB) ∪
  //   {featsb bf16 41MB ; msg bf16 42.6MB}]  (scores dead before loop starts)
  float* ws     = (float*)d_ws;
  float* adjval = ws;                                         //   409,600 f
  int*   adjcol = (int*)(adjval + 409600);                    //   409,600 i
  float* gate   = (float*)(adjcol + 409600);                  //        64 f
  unsigned short* Wt = (unsigned short*)(gate + 64);          //   692,224 f
  float* qk     = gate + 64 + 692224;                         // 3,276,800 f
  float* region = qk + (size_t)3276800;
  float* scores = region;                                     // 20,480,000 f
  unsigned short* featsb = (unsigned short*)region;           // 10,240,000 f-eq
  unsigned short* msg = (unsigned short*)(region + 10240000); // 10,649,600 f-eq
  float* fused  = (float*)msg;                                // MLP aliases dead msg
  float* h1     = fused + (size_t)6400 * 400;
  float* h2     = h1 + (size_t)6400 * 256;
  float* h3     = h2 + (size_t)6400 * 128;

  // 0. gcn_W -> bf16, transposed (n-major), zero-padded to 416x416
  wprep_k<<<dim3(13, 13, 8), dim3(32, 8), 0, stream>>>(gcnW, Wt);

  // 1. qk = x @ Wk + bk
  gemm_k<64, 64, 16, 4, 4, false><<<dim3(8, 100), 256, 0, stream>>>(
      x, Wk, bk, qk, 6400, 512, 400);

  // 2. SE gate
  gate_k<<<1, 64, 0, stream>>>(seW1, seb1, seW2, seb2, gate);

  // 3a. batched symmetric QK^T -> relu -> scores [51200,400]
  qkscore_k<<<dim3(7, 7, 128), 256, 0, stream>>>(qk, scores);

  // 3b. softmax+gate+rank -> 7-sparse adjacency (one wave per row)
  rankadj_k<<<12800, 256, 0, stream>>>(scores, gate, adjval, adjcol);

  // 4. 8x GCN: bf16-feats LDS-gather spmsg + barrier-free bf16 MFMA GEMM
  //    (layer 0 sources x directly for both gather and residual)
  for (int i = 0; i < 8; ++i) {
    const int first = (i == 0) ? 1 : 0;
    spmsg_k<<<dim3(26, BH), 256, 0, stream>>>(adjcol, adjval, featsb, x,
                                              first, msg);
    gcn_gemm<<<dim3(400, 7), 256, 0, stream>>>(
        msg, Wt + (size_t)i * KP * KP, gcnb + (size_t)i * nT, featsb, x, first);
  }

  // 5. fuse heads
  hfuse_k<<<2500, 256, 0, stream>>>(featsb, fw, fb, fused);

  // 6-9. MLP head (fp32)
  gemm_k<64, 64, 16, 4, 4, true><<<dim3(4, 100), 256, 0, stream>>>(
      fused, mW1, mb1, h1, 6400, 256, 400);
  gemm_k<64, 64, 16, 4, 4, true><<<dim3(2, 100), 256, 0, stream>>>(
      h1, mW2, mb2, h2, 6400, 128, 256);
  gemm_k<64, 64, 16, 4, 4, true><<<dim3(1, 100), 256, 0, stream>>>(
      h2, mW3, mb3, h3, 6400, 64, 128);
  gemm_k<64, 64, 16, 4, 4, true><<<dim3(1, 100), 256, 0, stream>>>(
      h3, mW4, mb4, out, 6400, 5, 64);
}